// Round 2
// baseline (367.943 us; speedup 1.0000x reference)
//
#include <hip/hip_runtime.h>

// Winograd F(2x2,3x3) with fixed Laplacian filter.
// Per tile: D = B x B^T ; Y = F .* D ; O = A Y A^T  (F precomputed).
//
// F = G @ FILT @ G^T =
//   [[ 0.0, -0.5,  0.5,  0.0],
//    [-0.5,  0.0, -1.0, -0.5],
//    [ 0.5, -1.0,  2.0,  0.5],
//    [ 0.0, -0.5,  0.5,  0.0]]
//
// Memory-bound: 80 B/tile. R1 fix: R0's per-thread tile loads were
// stride-64B per instruction (64 cache lines/instr -> address-path bound,
// 0.9 TB/s). Now: coalesced global->LDS staging, per-thread tile reads
// from LDS, coalesced float4 store. LDS bank aliasing on the 64B-stride
// ds_read_b128 is harmless (LDS BW >> HBM BW needed here).

#define TPB 256  // threads per block == tiles per block

__global__ __launch_bounds__(TPB) void winograd_tile_kernel(
    const float4* __restrict__ x4,   // [n_tiles*4] rows of 4 floats
    float4* __restrict__ out4,       // [n_tiles] (2x2 output per tile)
    int n_tiles)
{
    __shared__ float4 lds[TPB * 4];  // 16 KiB: 256 tiles x 4 rows

    const int tid = threadIdx.x;
    const int blk = blockIdx.x;
    const long long base = (long long)blk * (TPB * 4);  // first float4 row of block
    const long long total_rows = (long long)n_tiles * 4;

    // Coalesced staging: 4 lane-contiguous dwordx4 loads -> linear LDS write.
#pragma unroll
    for (int k = 0; k < 4; ++k) {
        long long idx = base + tid + k * TPB;
        if (idx < total_rows) {
            lds[tid + k * TPB] = x4[idx];
        }
    }
    __syncthreads();

    const int t = blk * TPB + tid;
    if (t >= n_tiles) return;

    // Read own tile (64B-stride ds_read_b128; bank aliasing irrelevant here).
    float4 r0 = lds[4 * tid + 0];
    float4 r1 = lds[4 * tid + 1];
    float4 r2 = lds[4 * tid + 2];
    float4 r3 = lds[4 * tid + 3];

    float xin[4][4] = {
        {r0.x, r0.y, r0.z, r0.w},
        {r1.x, r1.y, r1.z, r1.w},
        {r2.x, r2.y, r2.z, r2.w},
        {r3.x, r3.y, r3.z, r3.w},
    };

    // Bx = B @ x  (B = [[1,0,-1,0],[0,1,1,0],[0,-1,1,0],[0,1,0,-1]])
    float bx[4][4];
#pragma unroll
    for (int c = 0; c < 4; ++c) {
        bx[0][c] = xin[0][c] - xin[2][c];
        bx[1][c] = xin[1][c] + xin[2][c];
        bx[2][c] = xin[2][c] - xin[1][c];
        bx[3][c] = xin[1][c] - xin[3][c];
    }

    // D = Bx @ B^T
    float D[4][4];
#pragma unroll
    for (int r = 0; r < 4; ++r) {
        D[r][0] = bx[r][0] - bx[r][2];
        D[r][1] = bx[r][1] + bx[r][2];
        D[r][2] = bx[r][2] - bx[r][1];
        D[r][3] = bx[r][1] - bx[r][3];
    }

    // Y = F .* D  (corners of F are zero)
    float Y[4][4];
    Y[0][0] = 0.0f;
    Y[0][1] = -0.5f * D[0][1];
    Y[0][2] =  0.5f * D[0][2];
    Y[0][3] = 0.0f;
    Y[1][0] = -0.5f * D[1][0];
    Y[1][1] = 0.0f;
    Y[1][2] = -1.0f * D[1][2];
    Y[1][3] = -0.5f * D[1][3];
    Y[2][0] =  0.5f * D[2][0];
    Y[2][1] = -1.0f * D[2][1];
    Y[2][2] =  2.0f * D[2][2];
    Y[2][3] =  0.5f * D[2][3];
    Y[3][0] = 0.0f;
    Y[3][1] = -0.5f * D[3][1];
    Y[3][2] =  0.5f * D[3][2];
    Y[3][3] = 0.0f;

    // AY = A @ Y  (A = [[1,1,1,0],[0,1,-1,-1]])
    float ay0[4], ay1[4];
#pragma unroll
    for (int c = 0; c < 4; ++c) {
        ay0[c] = Y[0][c] + Y[1][c] + Y[2][c];
        ay1[c] = Y[1][c] - Y[2][c] - Y[3][c];
    }

    // O = AY @ A^T  -> 2x2, stored as one float4 (coalesced)
    float4 o;
    o.x = ay0[0] + ay0[1] + ay0[2];
    o.y = ay0[1] - ay0[2] - ay0[3];
    o.z = ay1[0] + ay1[1] + ay1[2];
    o.w = ay1[1] - ay1[2] - ay1[3];

    out4[t] = o;
}

extern "C" void kernel_launch(void* const* d_in, const int* in_sizes, int n_in,
                              void* d_out, int out_size, void* d_ws, size_t ws_size,
                              hipStream_t stream)
{
    const float4* x4 = (const float4*)d_in[0];
    float4* out4 = (float4*)d_out;
    int n_tiles = in_sizes[0] / 16;

    int grid = (n_tiles + TPB - 1) / TPB;
    winograd_tile_kernel<<<grid, TPB, 0, stream>>>(x4, out4, n_tiles);
}